// Round 9
// baseline (454.802 us; speedup 1.0000x reference)
//
#include <hip/hip_runtime.h>
#include <hip/hip_bf16.h>
#include <math.h>

// Problem constants (fixed by the reference)
#define N_NODES 20000
#define N_EDGES 320000
#define DIM     128
#define HIDDEN  128
#define NH      4
#define C1      32
#define C2      128
#define VC1     132   // 128 v | 4 ak   (query term cancels in softmax)
#define LN_EPS  1e-5f

// ---------------- wave helpers ----------------
__device__ __forceinline__ float wave_sum(float v){
#pragma unroll
  for (int o = 32; o; o >>= 1) v += __shfl_xor(v, o, 64);
  return v;
}
__device__ __forceinline__ float wave_max(float v){
#pragma unroll
  for (int o = 32; o; o >>= 1) v = fmaxf(v, __shfl_xor(v, o, 64));
  return v;
}

// ---------------- edge_index dtype detect ----------------
__global__ __launch_bounds__(1024) void detect_kernel(const int* __restrict__ ei32,
                                                      int* __restrict__ flag){
  __shared__ int any;
  if (threadIdx.x == 0) any = 0;
  __syncthreads();
  if (ei32[2 * threadIdx.x + 1] != 0) atomicOr(&any, 1);
  __syncthreads();
  if (threadIdx.x == 0) *flag = (any == 0) ? 1 : 0;
}

// ---------------- CSR build ----------------
__global__ void hist_kernel(const int* __restrict__ ei, const int* __restrict__ flag,
                            int* __restrict__ counts){
  const bool wide = (*flag != 0);
  for (int e = blockIdx.x * blockDim.x + threadIdx.x; e < N_EDGES;
       e += gridDim.x * blockDim.x){
    int d = wide ? ei[2 * (N_EDGES + e)] : ei[N_EDGES + e];   // dst row
    atomicAdd(&counts[d], 1);
  }
}

__global__ __launch_bounds__(1024) void scan_kernel(const int* __restrict__ counts,
    int* __restrict__ row_ptr, int* __restrict__ fill_ptr){
  const int PER = 20;                 // 1024*20 = 20480 >= 20000
  int t = threadIdx.x;
  int base = t * PER;
  int local[PER];
  int s = 0;
#pragma unroll
  for (int i = 0; i < PER; i++){
    int idx = base + i;
    int c = (idx < N_NODES) ? counts[idx] : 0;
    s += c; local[i] = s;             // inclusive within thread
  }
  __shared__ int bs[1024];
  bs[t] = s; __syncthreads();
  for (int off = 1; off < 1024; off <<= 1){
    int v = (t >= off) ? bs[t - off] : 0;
    __syncthreads();
    bs[t] += v;
    __syncthreads();
  }
  int excl = bs[t] - s;
  int prev = 0;
#pragma unroll
  for (int i = 0; i < PER; i++){
    int idx = base + i;
    if (idx < N_NODES){
      row_ptr[idx + 1] = excl + local[i];
      fill_ptr[idx]    = excl + prev;
    }
    prev = local[i];
  }
  if (t == 0) row_ptr[0] = 0;
}

__global__ void scatter_kernel(const int* __restrict__ ei, const int* __restrict__ flag,
                               int* __restrict__ fill_ptr, int* __restrict__ col_idx){
  const bool wide = (*flag != 0);
  for (int e = blockIdx.x * blockDim.x + threadIdx.x; e < N_EDGES;
       e += gridDim.x * blockDim.x){
    int d = wide ? ei[2 * (N_EDGES + e)] : ei[N_EDGES + e];
    int s = wide ? ei[2 * e]             : ei[e];
    int pos = atomicAdd(&fill_ptr[d], 1);
    col_idx[pos] = s;
  }
}

// ---------------- ak weight fold: Wka[k][h] = sum_c Wk[k][h*C+c]*att[h][C+c] ------
// (bk bias dropped: a per-head constant shift cancels in segment softmax)
__global__ void prep_ak_weights(const float* __restrict__ Wk1, const float* __restrict__ att1,
                                const float* __restrict__ Wk2, const float* __restrict__ att2,
                                float* __restrict__ Wka1, float* __restrict__ Wka2){
  int tid = blockIdx.x * blockDim.x + threadIdx.x;
  int stride = gridDim.x * blockDim.x;
  for (int idx = tid; idx < 128 * NH; idx += stride){
    int k = idx >> 2, h = idx & 3;
    float s = 0.f;
    for (int c = 0; c < C1; c++)
      s += Wk1[k * 128 + h * C1 + c] * att1[h * 2 * C1 + C1 + c];
    Wka1[idx] = s;
  }
  for (int idx = tid; idx < 128 * NH; idx += stride){
    int k = idx >> 2, h = idx & 3;
    float s = 0.f;
    for (int c = 0; c < C2; c++)
      s += Wk2[k * 512 + h * C2 + c] * att2[h * 2 * C2 + C2 + c];
    Wka2[idx] = s;
  }
}

// ---------------- W2r[h*128+k][c] = Wv2[k][h*128+c]; mb[c] = 0.25*sum_h bv2[h*128+c]
__global__ void prep_w2r(const float* __restrict__ Wv2, const float* __restrict__ bv2,
                         float* __restrict__ W2r, float* __restrict__ mb){
  int tid = blockIdx.x * blockDim.x + threadIdx.x;
  if (tid < 16384){
    int hk = tid >> 5;          // 0..511
    int c4 = (tid & 31) << 2;   // 0..124
    int h = hk >> 7, k = hk & 127;
    *(float4*)&W2r[(size_t)hk * 128 + c4] =
        *(const float4*)&Wv2[(size_t)k * 512 + h * 128 + c4];
  }
  if (tid < 32){
    int c4 = tid << 2;
    float4 b0 = *(const float4*)&bv2[c4];
    float4 b1 = *(const float4*)&bv2[128 + c4];
    float4 b2 = *(const float4*)&bv2[256 + c4];
    float4 b3 = *(const float4*)&bv2[384 + c4];
    *(float4*)&mb[c4] = make_float4(0.25f * (b0.x + b1.x + b2.x + b3.x),
                                    0.25f * (b0.y + b1.y + b2.y + b3.y),
                                    0.25f * (b0.z + b1.z + b2.z + b3.z),
                                    0.25f * (b0.w + b1.w + b2.w + b3.w));
  }
}

// ---------------- akgemv: dst[n][V+h] = sum_k hin[n][k] * Wka[k][h] ----------------
__global__ __launch_bounds__(256) void akgemv(const float* __restrict__ hin,
    const float* __restrict__ Wka, float* __restrict__ dst, int V, int VC){
  int wid = threadIdx.x >> 6, lane = threadIdx.x & 63;
  int n = blockIdx.x * 4 + wid;
  if (n >= N_NODES) return;
  float2 hv = *(const float2*)&hin[(size_t)n * 128 + (lane << 1)];
  float4 wa = *(const float4*)&Wka[lane << 3];
  float4 wb = *(const float4*)&Wka[(lane << 3) + 4];
  float p0 = hv.x * wa.x + hv.y * wb.x;
  float p1 = hv.x * wa.y + hv.y * wb.y;
  float p2 = hv.x * wa.z + hv.y * wb.z;
  float p3 = hv.x * wa.w + hv.y * wb.w;
  p0 = wave_sum(p0); p1 = wave_sum(p1); p2 = wave_sum(p2); p3 = wave_sum(p3);
  if (lane == 0)
    *(float4*)&dst[(size_t)n * VC + V] = make_float4(p0, p1, p2, p3);
}

// ---------------- scalar-broadcast f32 GEMM (no LDS, X-prefetch) -------------------
// Wave layout: lane = row (64 rows/wave), 16 wave-uniform cols per wave
// (4 waves/block -> 64-col tile). W via scalar loads (uniform col0). X is
// double-buffered in registers, 32 k per chunk: 8 independent float4 loads
// issued BEFORE the 512 FMAs of the previous chunk -> HBM latency hidden.
__device__ __forceinline__ void fma16(float xv, const float* __restrict__ wr,
                                      float (&acc)[16]){
  float4 wa = *(const float4*)(wr);
  float4 wb = *(const float4*)(wr + 4);
  float4 wc = *(const float4*)(wr + 8);
  float4 wd = *(const float4*)(wr + 12);
  acc[0]  = fmaf(xv, wa.x, acc[0]);  acc[1]  = fmaf(xv, wa.y, acc[1]);
  acc[2]  = fmaf(xv, wa.z, acc[2]);  acc[3]  = fmaf(xv, wa.w, acc[3]);
  acc[4]  = fmaf(xv, wb.x, acc[4]);  acc[5]  = fmaf(xv, wb.y, acc[5]);
  acc[6]  = fmaf(xv, wb.z, acc[6]);  acc[7]  = fmaf(xv, wb.w, acc[7]);
  acc[8]  = fmaf(xv, wc.x, acc[8]);  acc[9]  = fmaf(xv, wc.y, acc[9]);
  acc[10] = fmaf(xv, wc.z, acc[10]); acc[11] = fmaf(xv, wc.w, acc[11]);
  acc[12] = fmaf(xv, wd.x, acc[12]); acc[13] = fmaf(xv, wd.y, acc[13]);
  acc[14] = fmaf(xv, wd.z, acc[14]); acc[15] = fmaf(xv, wd.w, acc[15]);
}

template <int M>
__device__ __forceinline__ void comp_chunk(const float4 (&buf)[8],
    const float* __restrict__ Wc, int kb, float (&acc)[16]){
#pragma unroll
  for (int i = 0; i < 8; i++){
    const float* w0 = Wc + (size_t)(kb + 4 * i) * M;
    fma16(buf[i].x, w0,         acc);
    fma16(buf[i].y, w0 + M,     acc);
    fma16(buf[i].z, w0 + 2 * M, acc);
    fma16(buf[i].w, w0 + 3 * M, acc);
  }
}

template <int ACT, int K, int M>  // ACT: 0 = none, 1 = relu
__global__ __launch_bounds__(256) void gemm_sb(const float* __restrict__ X,
    const float* __restrict__ W, const float* __restrict__ bias,
    float* __restrict__ Y, int ldY){
  const int lane = threadIdx.x & 63;
  const int col0 = __builtin_amdgcn_readfirstlane(
      blockIdx.y * 64 + ((threadIdx.x >> 6) << 4));
  const int row = blockIdx.x * 64 + lane;
  int rclamp = row < N_NODES ? row : N_NODES - 1;
  const float4* xr4 = (const float4*)(X + (size_t)rclamp * K);
  const float* Wc = W + col0;
  float acc[16];
#pragma unroll
  for (int c = 0; c < 16; c++) acc[c] = 0.f;
  float4 bufA[8], bufB[8];
  constexpr int NC = K / 32;          // chunks of 32 k (K=128 -> 4, K=512 -> 16)
#pragma unroll
  for (int i = 0; i < 8; i++) bufA[i] = xr4[i];
  for (int c = 0; c < NC; c += 2){
    // prefetch chunk c+1 before computing chunk c (NC even -> c+1 < NC)
#pragma unroll
    for (int i = 0; i < 8; i++) bufB[i] = xr4[(c + 1) * 8 + i];
    comp_chunk<M>(bufA, Wc, c * 32, acc);
    if (c + 2 < NC){
#pragma unroll
      for (int i = 0; i < 8; i++) bufA[i] = xr4[(c + 2) * 8 + i];
    }
    comp_chunk<M>(bufB, Wc, (c + 1) * 32, acc);
  }
  if (row < N_NODES){
    float* yr = Y + (size_t)row * ldY + col0;
#pragma unroll
    for (int j = 0; j < 4; j++){
      float4 b4 = *(const float4*)&bias[col0 + 4 * j];
      float4 o;
      o.x = acc[4*j]     + b4.x; o.y = acc[4*j + 1] + b4.y;
      o.z = acc[4*j + 2] + b4.z; o.w = acc[4*j + 3] + b4.w;
      if (ACT == 1){
        o.x = fmaxf(o.x, 0.f); o.y = fmaxf(o.y, 0.f);
        o.z = fmaxf(o.z, 0.f); o.w = fmaxf(o.w, 0.f);
      }
      *(float4*)(yr + 4 * j) = o;
    }
  }
}

// ---------------- layer 0: GAT (concat heads) + residual + LN + relu ----------------
__global__ __launch_bounds__(256) void gat0(const float* __restrict__ vcat,
    const int* __restrict__ row_ptr, const int* __restrict__ col_idx,
    const float* __restrict__ hres, const float* __restrict__ g,
    const float* __restrict__ beta, float* __restrict__ out){
  __shared__ float exs[4][256];
  int wid = threadIdx.x >> 6;
  int lane = threadIdx.x & 63;
  int n = blockIdx.x * 4 + wid;
  if (n >= N_NODES) return;
  int start = row_ptr[n], end = row_ptr[n + 1];
  float m0 = -1e30f, m1 = -1e30f, m2 = -1e30f, m3 = -1e30f;
  for (int e = start + lane; e < end; e += 64){
    int s = col_idx[e];
    const float4 ak = *(const float4*)&vcat[(size_t)s * VC1 + 128];
    m0 = fmaxf(m0, ak.x); m1 = fmaxf(m1, ak.y);
    m2 = fmaxf(m2, ak.z); m3 = fmaxf(m3, ak.w);
  }
  m0 = wave_max(m0); m1 = wave_max(m1); m2 = wave_max(m2); m3 = wave_max(m3);
  int l5 = lane >> 5;                 // half-wave id (edge parity)
  int c4 = (lane & 31) << 2;          // my 4 channels
  int h  = (lane & 31) >> 3;          // their head
  float a0 = 0.f, a1 = 0.f, a2 = 0.f, a3 = 0.f;
  float s0 = 0.f, s1 = 0.f, s2 = 0.f, s3 = 0.f;
  for (int base = start; base < end; base += 64){
    int e = base + lane;
    float4 ex = make_float4(0.f, 0.f, 0.f, 0.f);
    int srcj = 0;
    if (e < end){
      srcj = col_idx[e];
      const float4 ak = *(const float4*)&vcat[(size_t)srcj * VC1 + 128];
      ex.x = __expf(ak.x - m0); ex.y = __expf(ak.y - m1);
      ex.z = __expf(ak.z - m2); ex.w = __expf(ak.w - m3);
      s0 += ex.x; s1 += ex.y; s2 += ex.z; s3 += ex.w;
    }
    *(float4*)&exs[wid][lane << 2] = ex;
    __builtin_amdgcn_wave_barrier();
    int cnt = end - base; if (cnt > 64) cnt = 64;
    int half = (cnt + 1) >> 1;
    for (int j = 0; j < half; ++j){
      int jj = 2 * j + l5;
      int jjc = (jj < cnt) ? jj : 0;
      int sj = __shfl(srcj, jjc, 64);
      if (jj < cnt){
        float eh = exs[wid][(jj << 2) + h];
        const float4 v = *(const float4*)&vcat[(size_t)sj * VC1 + c4];
        a0 = fmaf(eh, v.x, a0); a1 = fmaf(eh, v.y, a1);
        a2 = fmaf(eh, v.z, a2); a3 = fmaf(eh, v.w, a3);
      }
    }
    __builtin_amdgcn_wave_barrier();
  }
  a0 += __shfl_xor(a0, 32, 64); a1 += __shfl_xor(a1, 32, 64);
  a2 += __shfl_xor(a2, 32, 64); a3 += __shfl_xor(a3, 32, 64);
  s0 = wave_sum(s0); s1 = wave_sum(s1); s2 = wave_sum(s2); s3 = wave_sum(s3);
  float sh = (h == 0) ? s0 : (h == 1) ? s1 : (h == 2) ? s2 : s3;
  sh = fmaxf(sh, 1e-16f);
  float inv = 1.f / sh;
  const float4 r = *(const float4*)&hres[(size_t)n * HIDDEN + c4];
  float v0 = a0 * inv + r.x, v1 = a1 * inv + r.y;
  float v2 = a2 * inv + r.z, v3 = a3 * inv + r.w;
  float mean = wave_sum(v0 + v1 + v2 + v3) * (1.f / 256.f);
  float d0 = v0 - mean, d1 = v1 - mean, d2 = v2 - mean, d3 = v3 - mean;
  float var = wave_sum(d0*d0 + d1*d1 + d2*d2 + d3*d3) * (1.f / 256.f);
  float rs = rsqrtf(var + LN_EPS);
  const float4 g4 = *(const float4*)&g[c4];
  const float4 b4 = *(const float4*)&beta[c4];
  if (l5 == 0){
    float4 o;
    o.x = fmaxf(d0 * rs * g4.x + b4.x, 0.f);
    o.y = fmaxf(d1 * rs * g4.y + b4.y, 0.f);
    o.z = fmaxf(d2 * rs * g4.z + b4.z, 0.f);
    o.w = fmaxf(d3 * rs * g4.w + b4.w, 0.f);
    *(float4*)&out[(size_t)n * HIDDEN + c4] = o;
  }
}

// ---------------- layer 1 aggregation: u[n][h*128+c] = 0.25/s_h * sum_j a[e,h]*h2[j][c]
// Gathers h2 rows (512B/edge) instead of 2KB vcat rows; projection deferred to
// a K=512 GEMM (linearity of v = Wv^T h). Half-wave per edge, 4 head accs/lane.
__global__ __launch_bounds__(256) void gat1_agg(const float* __restrict__ h2,
    const float* __restrict__ ak2,
    const int* __restrict__ row_ptr, const int* __restrict__ col_idx,
    float* __restrict__ u){
  __shared__ float exs[4][256];
  int wid = threadIdx.x >> 6;
  int lane = threadIdx.x & 63;
  int n = blockIdx.x * 4 + wid;
  if (n >= N_NODES) return;
  int start = row_ptr[n], end = row_ptr[n + 1];
  float m0 = -1e30f, m1 = -1e30f, m2 = -1e30f, m3 = -1e30f;
  for (int e = start + lane; e < end; e += 64){
    const float4 a = *(const float4*)&ak2[(size_t)col_idx[e] * 4];
    m0 = fmaxf(m0, a.x); m1 = fmaxf(m1, a.y);
    m2 = fmaxf(m2, a.z); m3 = fmaxf(m3, a.w);
  }
  m0 = wave_max(m0); m1 = wave_max(m1); m2 = wave_max(m2); m3 = wave_max(m3);
  int l5 = lane >> 5;                 // half-wave id (edge parity)
  int c4 = (lane & 31) << 2;          // my 4 channels of h2
  float acc[4][4] = {{0.f}};          // [head][chan]
  float s0 = 0.f, s1 = 0.f, s2 = 0.f, s3 = 0.f;
  for (int base = start; base < end; base += 64){
    int e = base + lane;
    float4 ex = make_float4(0.f, 0.f, 0.f, 0.f);
    int srcj = 0;
    if (e < end){
      srcj = col_idx[e];
      const float4 a = *(const float4*)&ak2[(size_t)srcj * 4];
      ex.x = __expf(a.x - m0); ex.y = __expf(a.y - m1);
      ex.z = __expf(a.z - m2); ex.w = __expf(a.w - m3);
      s0 += ex.x; s1 += ex.y; s2 += ex.z; s3 += ex.w;
    }
    *(float4*)&exs[wid][lane << 2] = ex;
    __builtin_amdgcn_wave_barrier();
    int cnt = end - base; if (cnt > 64) cnt = 64;
    int half = (cnt + 1) >> 1;
    for (int j = 0; j < half; ++j){
      int jj = 2 * j + l5;
      int jjc = (jj < cnt) ? jj : 0;
      int sj = __shfl(srcj, jjc, 64);
      if (jj < cnt){
        const float4 eh = *(const float4*)&exs[wid][jj << 2];
        const float4 v = *(const float4*)&h2[(size_t)sj * 128 + c4];
        acc[0][0] = fmaf(eh.x, v.x, acc[0][0]); acc[0][1] = fmaf(eh.x, v.y, acc[0][1]);
        acc[0][2] = fmaf(eh.x, v.z, acc[0][2]); acc[0][3] = fmaf(eh.x, v.w, acc[0][3]);
        acc[1][0] = fmaf(eh.y, v.x, acc[1][0]); acc[1][1] = fmaf(eh.y, v.y, acc[1][1]);
        acc[1][2] = fmaf(eh.y, v.z, acc[1][2]); acc[1][3] = fmaf(eh.y, v.w, acc[1][3]);
        acc[2][0] = fmaf(eh.z, v.x, acc[2][0]); acc[2][1] = fmaf(eh.z, v.y, acc[2][1]);
        acc[2][2] = fmaf(eh.z, v.z, acc[2][2]); acc[2][3] = fmaf(eh.z, v.w, acc[2][3]);
        acc[3][0] = fmaf(eh.w, v.x, acc[3][0]); acc[3][1] = fmaf(eh.w, v.y, acc[3][1]);
        acc[3][2] = fmaf(eh.w, v.z, acc[3][2]); acc[3][3] = fmaf(eh.w, v.w, acc[3][3]);
      }
    }
    __builtin_amdgcn_wave_barrier();
  }
#pragma unroll
  for (int h = 0; h < 4; h++)
#pragma unroll
    for (int c = 0; c < 4; c++)
      acc[h][c] += __shfl_xor(acc[h][c], 32, 64);
  s0 = wave_sum(s0); s1 = wave_sum(s1); s2 = wave_sum(s2); s3 = wave_sum(s3);
  float w0 = 0.25f / fmaxf(s0, 1e-16f);
  float w1 = 0.25f / fmaxf(s1, 1e-16f);
  float w2 = 0.25f / fmaxf(s2, 1e-16f);
  float w3 = 0.25f / fmaxf(s3, 1e-16f);
  if (l5 == 0){
    float* ur = &u[(size_t)n * 512 + c4];
    *(float4*)(ur)       = make_float4(acc[0][0]*w0, acc[0][1]*w0, acc[0][2]*w0, acc[0][3]*w0);
    *(float4*)(ur + 128) = make_float4(acc[1][0]*w1, acc[1][1]*w1, acc[1][2]*w1, acc[1][3]*w1);
    *(float4*)(ur + 256) = make_float4(acc[2][0]*w2, acc[2][1]*w2, acc[2][2]*w2, acc[2][3]*w2);
    *(float4*)(ur + 384) = make_float4(acc[3][0]*w3, acc[3][1]*w3, acc[3][2]*w3, acc[3][3]*w3);
  }
}

// ---------------- residual + LN (in-place safe: out may alias hres) ----------------
__global__ __launch_bounds__(256) void ln_res(const float* __restrict__ o2,
    const float* hres, const float* __restrict__ g,
    const float* __restrict__ beta, float* out){
  int wid = threadIdx.x >> 6, lane = threadIdx.x & 63;
  int n = blockIdx.x * 4 + wid;
  if (n >= N_NODES) return;
  int c2 = lane << 1;
  float2 a = *(const float2*)&o2[(size_t)n * 128 + c2];
  float2 r = *(const float2*)&hres[(size_t)n * 128 + c2];
  float vx = a.x + r.x, vy = a.y + r.y;
  float mean = wave_sum(vx + vy) * (1.f / 128.f);
  float dx = vx - mean, dy = vy - mean;
  float var = wave_sum(dx * dx + dy * dy) * (1.f / 128.f);
  float rs = rsqrtf(var + LN_EPS);
  float2 gg = *(const float2*)&g[c2];
  float2 bb = *(const float2*)&beta[c2];
  *(float2*)&out[(size_t)n * 128 + c2] =
      make_float2(dx * rs * gg.x + bb.x, dy * rs * gg.y + bb.y);
}

// ---------------- launch ----------------
extern "C" void kernel_launch(void* const* d_in, const int* in_sizes, int n_in,
                              void* d_out, int out_size, void* d_ws, size_t ws_size,
                              hipStream_t stream) {
  const float* x     = (const float*)d_in[0];
  const int*   ei    = (const int*)  d_in[1];   // int32 or int64 -- detected on device
  const float* W_in  = (const float*)d_in[2];
  const float* b_in  = (const float*)d_in[3];
  const float* Wk1   = (const float*)d_in[6];
  const float* Wv1   = (const float*)d_in[8];
  const float* bv1   = (const float*)d_in[9];
  const float* att1  = (const float*)d_in[10];
  const float* g1    = (const float*)d_in[11];
  const float* beta1 = (const float*)d_in[12];
  const float* Wk2   = (const float*)d_in[15];
  const float* Wv2   = (const float*)d_in[17];
  const float* bv2   = (const float*)d_in[18];
  const float* att2  = (const float*)d_in[19];
  const float* g2    = (const float*)d_in[20];
  const float* beta2 = (const float*)d_in[21];
  const float* W_out = (const float*)d_in[22];
  const float* b_out = (const float*)d_in[23];
  float* zout = (float*)d_out;

  char* base = (char*)d_ws;
  size_t off = 0;
  auto take = [&](size_t bytes) -> void* {
    void* p = base + off;
    off += (bytes + 255) & ~(size_t)255;
    return p;
  };
  float* h1      = (float*)take((size_t)N_NODES * 128 * 4);  // later reused as o2
  float* h2      = (float*)take((size_t)N_NODES * 128 * 4);  // later LN'd in place (h3)
  float* u       = (float*)take((size_t)N_NODES * 512 * 4);  // vcat1 aliases (dead before)
  float* vcat1   = u;
  float* ak2     = (float*)take((size_t)N_NODES * 4 * 4);
  float* Wka1    = (float*)take(128 * NH * 4);
  float* Wka2    = (float*)take(128 * NH * 4);
  float* W2r     = (float*)take(512 * 128 * 4);
  float* mb      = (float*)take(128 * 4);
  int*   counts  = (int*)take((size_t)N_NODES * 4);
  int*   row_ptr = (int*)take((size_t)(N_NODES + 1) * 4);
  int*   fillp   = (int*)take((size_t)N_NODES * 4);
  int*   col_idx = (int*)take((size_t)N_EDGES * 4);
  int*   eflag   = (int*)take(256);
  float* o2      = h1;      // h1 dead after gat0 consumes it
  float* h3      = h2;      // ln_res is in-place safe

  const int RT = (N_NODES + 63) / 64;   // 313 row tiles

  // CSR build
  hipMemsetAsync(counts, 0, (size_t)N_NODES * 4, stream);
  detect_kernel<<<1, 1024, 0, stream>>>(ei, eflag);
  hist_kernel<<<512, 256, 0, stream>>>(ei, eflag, counts);
  scan_kernel<<<1, 1024, 0, stream>>>(counts, row_ptr, fillp);
  scatter_kernel<<<512, 256, 0, stream>>>(ei, eflag, fillp, col_idx);

  prep_ak_weights<<<2, 256, 0, stream>>>(Wk1, att1, Wk2, att2, Wka1, Wka2);
  prep_w2r<<<64, 256, 0, stream>>>(Wv2, bv2, W2r, mb);

  // h1 = relu(x @ W_in + b_in)
  gemm_sb<1, 128, 128><<<dim3(RT, 2), 256, 0, stream>>>(x, W_in, b_in, h1, 128);
  // vcat1 v-part = h1 @ Wv1 + bv1 ; ak-part = h1 @ Wka1
  gemm_sb<0, 128, 128><<<dim3(RT, 2), 256, 0, stream>>>(h1, Wv1, bv1, vcat1, VC1);
  akgemv<<<(N_NODES + 3) / 4, 256, 0, stream>>>(h1, Wka1, vcat1, 128, VC1);
  // layer 0 aggregation + residual + LN + relu -> h2
  gat0<<<N_NODES / 4, 256, 0, stream>>>(vcat1, row_ptr, col_idx, h1, g1, beta1, h2);
  // layer 1: ak2 then aggregated features u (projection deferred)
  akgemv<<<(N_NODES + 3) / 4, 256, 0, stream>>>(h2, Wka2, ak2, 0, 4);
  gat1_agg<<<N_NODES / 4, 256, 0, stream>>>(h2, ak2, row_ptr, col_idx, u);
  // o2 = u @ W2r + mb   (= mean_h( (sum_j a_h h2_j) @ Wv2_h + bv2_h ))
  gemm_sb<0, 512, 128><<<dim3(RT, 2), 256, 0, stream>>>(u, W2r, mb, o2, 128);
  // h3 = LN(o2 + h2) * g2 + beta2   (in place over h2)
  ln_res<<<N_NODES / 4, 256, 0, stream>>>(o2, h2, g2, beta2, h3);
  // z = h3 @ W_out + b_out
  gemm_sb<0, 128, 128><<<dim3(RT, 2), 256, 0, stream>>>(h3, W_out, b_out, zout, 128);
}

// Round 10
// 360.909 us; speedup vs baseline: 1.2602x; 1.2602x over previous
//
#include <hip/hip_runtime.h>
#include <hip/hip_bf16.h>
#include <math.h>

// Problem constants (fixed by the reference)
#define N_NODES 20000
#define N_EDGES 320000
#define DIM     128
#define HIDDEN  128
#define NH      4
#define C1      32
#define C2      128
#define VC1     132   // 128 v | 4 ak   (query term cancels in softmax)
#define LN_EPS  1e-5f

// ---------------- wave helpers ----------------
__device__ __forceinline__ float wave_sum(float v){
#pragma unroll
  for (int o = 32; o; o >>= 1) v += __shfl_xor(v, o, 64);
  return v;
}
__device__ __forceinline__ float wave_max(float v){
#pragma unroll
  for (int o = 32; o; o >>= 1) v = fmaxf(v, __shfl_xor(v, o, 64));
  return v;
}

// ---------------- edge_index dtype detect ----------------
__global__ __launch_bounds__(1024) void detect_kernel(const int* __restrict__ ei32,
                                                      int* __restrict__ flag){
  __shared__ int any;
  if (threadIdx.x == 0) any = 0;
  __syncthreads();
  if (ei32[2 * threadIdx.x + 1] != 0) atomicOr(&any, 1);
  __syncthreads();
  if (threadIdx.x == 0) *flag = (any == 0) ? 1 : 0;
}

// ---------------- CSR build ----------------
__global__ void hist_kernel(const int* __restrict__ ei, const int* __restrict__ flag,
                            int* __restrict__ counts){
  const bool wide = (*flag != 0);
  for (int e = blockIdx.x * blockDim.x + threadIdx.x; e < N_EDGES;
       e += gridDim.x * blockDim.x){
    int d = wide ? ei[2 * (N_EDGES + e)] : ei[N_EDGES + e];   // dst row
    atomicAdd(&counts[d], 1);
  }
}

__global__ __launch_bounds__(1024) void scan_kernel(const int* __restrict__ counts,
    int* __restrict__ row_ptr, int* __restrict__ fill_ptr){
  const int PER = 20;                 // 1024*20 = 20480 >= 20000
  int t = threadIdx.x;
  int base = t * PER;
  int local[PER];
  int s = 0;
#pragma unroll
  for (int i = 0; i < PER; i++){
    int idx = base + i;
    int c = (idx < N_NODES) ? counts[idx] : 0;
    s += c; local[i] = s;             // inclusive within thread
  }
  __shared__ int bs[1024];
  bs[t] = s; __syncthreads();
  for (int off = 1; off < 1024; off <<= 1){
    int v = (t >= off) ? bs[t - off] : 0;
    __syncthreads();
    bs[t] += v;
    __syncthreads();
  }
  int excl = bs[t] - s;
  int prev = 0;
#pragma unroll
  for (int i = 0; i < PER; i++){
    int idx = base + i;
    if (idx < N_NODES){
      row_ptr[idx + 1] = excl + local[i];
      fill_ptr[idx]    = excl + prev;
    }
    prev = local[i];
  }
  if (t == 0) row_ptr[0] = 0;
}

__global__ void scatter_kernel(const int* __restrict__ ei, const int* __restrict__ flag,
                               int* __restrict__ fill_ptr, int* __restrict__ col_idx){
  const bool wide = (*flag != 0);
  for (int e = blockIdx.x * blockDim.x + threadIdx.x; e < N_EDGES;
       e += gridDim.x * blockDim.x){
    int d = wide ? ei[2 * (N_EDGES + e)] : ei[N_EDGES + e];
    int s = wide ? ei[2 * e]             : ei[e];
    int pos = atomicAdd(&fill_ptr[d], 1);
    col_idx[pos] = s;
  }
}

// ---------------- ak weight fold: Wka[k][h] = sum_c Wk[k][h*C+c]*att[h][C+c] ------
// (bk bias dropped: a per-head constant shift cancels in segment softmax)
__global__ void prep_ak_weights(const float* __restrict__ Wk1, const float* __restrict__ att1,
                                const float* __restrict__ Wk2, const float* __restrict__ att2,
                                float* __restrict__ Wka1, float* __restrict__ Wka2){
  int tid = blockIdx.x * blockDim.x + threadIdx.x;
  int stride = gridDim.x * blockDim.x;
  for (int idx = tid; idx < 128 * NH; idx += stride){
    int k = idx >> 2, h = idx & 3;
    float s = 0.f;
    for (int c = 0; c < C1; c++)
      s += Wk1[k * 128 + h * C1 + c] * att1[h * 2 * C1 + C1 + c];
    Wka1[idx] = s;
  }
  for (int idx = tid; idx < 128 * NH; idx += stride){
    int k = idx >> 2, h = idx & 3;
    float s = 0.f;
    for (int c = 0; c < C2; c++)
      s += Wk2[k * 512 + h * C2 + c] * att2[h * 2 * C2 + C2 + c];
    Wka2[idx] = s;
  }
}

// ---------------- W2r[h*128+k][c] = Wv2[k][h*128+c]; mb[c] = 0.25*sum_h bv2[h*128+c]
__global__ void prep_w2r(const float* __restrict__ Wv2, const float* __restrict__ bv2,
                         float* __restrict__ W2r, float* __restrict__ mb){
  int tid = blockIdx.x * blockDim.x + threadIdx.x;
  if (tid < 16384){
    int hk = tid >> 5;          // 0..511
    int c4 = (tid & 31) << 2;   // 0..124
    int h = hk >> 7, k = hk & 127;
    *(float4*)&W2r[(size_t)hk * 128 + c4] =
        *(const float4*)&Wv2[(size_t)k * 512 + h * 128 + c4];
  }
  if (tid < 32){
    int c4 = tid << 2;
    float4 b0 = *(const float4*)&bv2[c4];
    float4 b1 = *(const float4*)&bv2[128 + c4];
    float4 b2 = *(const float4*)&bv2[256 + c4];
    float4 b3 = *(const float4*)&bv2[384 + c4];
    *(float4*)&mb[c4] = make_float4(0.25f * (b0.x + b1.x + b2.x + b3.x),
                                    0.25f * (b0.y + b1.y + b2.y + b3.y),
                                    0.25f * (b0.z + b1.z + b2.z + b3.z),
                                    0.25f * (b0.w + b1.w + b2.w + b3.w));
  }
}

// ---------------- akgemv: dst[n][V+h] = sum_k hin[n][k] * Wka[k][h] ----------------
__global__ __launch_bounds__(256) void akgemv(const float* __restrict__ hin,
    const float* __restrict__ Wka, float* __restrict__ dst, int V, int VC){
  int wid = threadIdx.x >> 6, lane = threadIdx.x & 63;
  int n = blockIdx.x * 4 + wid;
  if (n >= N_NODES) return;
  float2 hv = *(const float2*)&hin[(size_t)n * 128 + (lane << 1)];
  float4 wa = *(const float4*)&Wka[lane << 3];
  float4 wb = *(const float4*)&Wka[(lane << 3) + 4];
  float p0 = hv.x * wa.x + hv.y * wb.x;
  float p1 = hv.x * wa.y + hv.y * wb.y;
  float p2 = hv.x * wa.z + hv.y * wb.z;
  float p3 = hv.x * wa.w + hv.y * wb.w;
  p0 = wave_sum(p0); p1 = wave_sum(p1); p2 = wave_sum(p2); p3 = wave_sum(p3);
  if (lane == 0)
    *(float4*)&dst[(size_t)n * VC + V] = make_float4(p0, p1, p2, p3);
}

// ---------------- scalar-broadcast f32 GEMM (no LDS) — round-8 verified body ------
// Wave layout: lane = row (64 rows/wave), 16 wave-uniform cols per wave
// (4 waves/block -> 64-col tile). Per k: 1 cached X dword/lane + 4 uniform
// float4 W loads (SGPR via readfirstlane) + 16 FMA. 16 VGPR, no barriers.
template <int ACT, int K>  // ACT: 0 = none, 1 = relu
__global__ __launch_bounds__(256) void gemm_sb(const float* __restrict__ X,
    const float* __restrict__ W, const float* __restrict__ bias,
    float* __restrict__ Y, int M, int ldY){
  const int lane = threadIdx.x & 63;
  const int col0 = __builtin_amdgcn_readfirstlane(
      blockIdx.y * 64 + ((threadIdx.x >> 6) << 4));
  const int row = blockIdx.x * 64 + lane;
  int rclamp = row < N_NODES ? row : N_NODES - 1;
  const float* xr = X + (size_t)rclamp * K;
  float acc[16];
#pragma unroll
  for (int c = 0; c < 16; c++) acc[c] = 0.f;
#pragma unroll 4
  for (int k = 0; k < K; ++k){
    float xv = xr[k];
    const float* wr = W + (size_t)k * M + col0;
    float4 wa = *(const float4*)(wr);
    float4 wb = *(const float4*)(wr + 4);
    float4 wc = *(const float4*)(wr + 8);
    float4 wd = *(const float4*)(wr + 12);
    acc[0]  = fmaf(xv, wa.x, acc[0]);  acc[1]  = fmaf(xv, wa.y, acc[1]);
    acc[2]  = fmaf(xv, wa.z, acc[2]);  acc[3]  = fmaf(xv, wa.w, acc[3]);
    acc[4]  = fmaf(xv, wb.x, acc[4]);  acc[5]  = fmaf(xv, wb.y, acc[5]);
    acc[6]  = fmaf(xv, wb.z, acc[6]);  acc[7]  = fmaf(xv, wb.w, acc[7]);
    acc[8]  = fmaf(xv, wc.x, acc[8]);  acc[9]  = fmaf(xv, wc.y, acc[9]);
    acc[10] = fmaf(xv, wc.z, acc[10]); acc[11] = fmaf(xv, wc.w, acc[11]);
    acc[12] = fmaf(xv, wd.x, acc[12]); acc[13] = fmaf(xv, wd.y, acc[13]);
    acc[14] = fmaf(xv, wd.z, acc[14]); acc[15] = fmaf(xv, wd.w, acc[15]);
  }
  if (row < N_NODES){
    float* yr = Y + (size_t)row * ldY + col0;
#pragma unroll
    for (int j = 0; j < 4; j++){
      float4 b4 = *(const float4*)&bias[col0 + 4 * j];
      float4 o;
      o.x = acc[4*j]     + b4.x; o.y = acc[4*j + 1] + b4.y;
      o.z = acc[4*j + 2] + b4.z; o.w = acc[4*j + 3] + b4.w;
      if (ACT == 1){
        o.x = fmaxf(o.x, 0.f); o.y = fmaxf(o.y, 0.f);
        o.z = fmaxf(o.z, 0.f); o.w = fmaxf(o.w, 0.f);
      }
      *(float4*)(yr + 4 * j) = o;
    }
  }
}

// ---------------- K-split GEMM for o2: K=512 in 2 splits of 256 k ------------------
// Same round-8 body; blockIdx.z picks the k-range and the partial output plane.
// No bias (folded into ln_res4 via mb). Doubles waves/CU to hide HBM latency.
__global__ __launch_bounds__(256) void gemm_ks(const float* __restrict__ X,
    const float* __restrict__ W, float* __restrict__ P0, float* __restrict__ P1){
  const int lane = threadIdx.x & 63;
  const int col0 = __builtin_amdgcn_readfirstlane(
      blockIdx.y * 64 + ((threadIdx.x >> 6) << 4));
  const int kb = __builtin_amdgcn_readfirstlane(blockIdx.z * 256);
  const int row = blockIdx.x * 64 + lane;
  int rclamp = row < N_NODES ? row : N_NODES - 1;
  const float* xr = X + (size_t)rclamp * 512 + kb;
  float acc[16];
#pragma unroll
  for (int c = 0; c < 16; c++) acc[c] = 0.f;
#pragma unroll 4
  for (int k = 0; k < 256; ++k){
    float xv = xr[k];
    const float* wr = W + (size_t)(kb + k) * 128 + col0;
    float4 wa = *(const float4*)(wr);
    float4 wb = *(const float4*)(wr + 4);
    float4 wc = *(const float4*)(wr + 8);
    float4 wd = *(const float4*)(wr + 12);
    acc[0]  = fmaf(xv, wa.x, acc[0]);  acc[1]  = fmaf(xv, wa.y, acc[1]);
    acc[2]  = fmaf(xv, wa.z, acc[2]);  acc[3]  = fmaf(xv, wa.w, acc[3]);
    acc[4]  = fmaf(xv, wb.x, acc[4]);  acc[5]  = fmaf(xv, wb.y, acc[5]);
    acc[6]  = fmaf(xv, wb.z, acc[6]);  acc[7]  = fmaf(xv, wb.w, acc[7]);
    acc[8]  = fmaf(xv, wc.x, acc[8]);  acc[9]  = fmaf(xv, wc.y, acc[9]);
    acc[10] = fmaf(xv, wc.z, acc[10]); acc[11] = fmaf(xv, wc.w, acc[11]);
    acc[12] = fmaf(xv, wd.x, acc[12]); acc[13] = fmaf(xv, wd.y, acc[13]);
    acc[14] = fmaf(xv, wd.z, acc[14]); acc[15] = fmaf(xv, wd.w, acc[15]);
  }
  if (row < N_NODES){
    float* P = blockIdx.z ? P1 : P0;
    float* yr = P + (size_t)row * 128 + col0;
#pragma unroll
    for (int j = 0; j < 4; j++)
      *(float4*)(yr + 4 * j) = make_float4(acc[4*j], acc[4*j+1], acc[4*j+2], acc[4*j+3]);
  }
}

// ---------------- layer 0: GAT (concat heads) + residual + LN + relu ----------------
__global__ __launch_bounds__(256) void gat0(const float* __restrict__ vcat,
    const int* __restrict__ row_ptr, const int* __restrict__ col_idx,
    const float* __restrict__ hres, const float* __restrict__ g,
    const float* __restrict__ beta, float* __restrict__ out){
  __shared__ float exs[4][256];
  int wid = threadIdx.x >> 6;
  int lane = threadIdx.x & 63;
  int n = blockIdx.x * 4 + wid;
  if (n >= N_NODES) return;
  int start = row_ptr[n], end = row_ptr[n + 1];
  float m0 = -1e30f, m1 = -1e30f, m2 = -1e30f, m3 = -1e30f;
  for (int e = start + lane; e < end; e += 64){
    int s = col_idx[e];
    const float4 ak = *(const float4*)&vcat[(size_t)s * VC1 + 128];
    m0 = fmaxf(m0, ak.x); m1 = fmaxf(m1, ak.y);
    m2 = fmaxf(m2, ak.z); m3 = fmaxf(m3, ak.w);
  }
  m0 = wave_max(m0); m1 = wave_max(m1); m2 = wave_max(m2); m3 = wave_max(m3);
  int l5 = lane >> 5;                 // half-wave id (edge parity)
  int c4 = (lane & 31) << 2;          // my 4 channels
  int h  = (lane & 31) >> 3;          // their head
  float a0 = 0.f, a1 = 0.f, a2 = 0.f, a3 = 0.f;
  float s0 = 0.f, s1 = 0.f, s2 = 0.f, s3 = 0.f;
  for (int base = start; base < end; base += 64){
    int e = base + lane;
    float4 ex = make_float4(0.f, 0.f, 0.f, 0.f);
    int srcj = 0;
    if (e < end){
      srcj = col_idx[e];
      const float4 ak = *(const float4*)&vcat[(size_t)srcj * VC1 + 128];
      ex.x = __expf(ak.x - m0); ex.y = __expf(ak.y - m1);
      ex.z = __expf(ak.z - m2); ex.w = __expf(ak.w - m3);
      s0 += ex.x; s1 += ex.y; s2 += ex.z; s3 += ex.w;
    }
    *(float4*)&exs[wid][lane << 2] = ex;
    __builtin_amdgcn_wave_barrier();
    int cnt = end - base; if (cnt > 64) cnt = 64;
    int half = (cnt + 1) >> 1;
    for (int j = 0; j < half; ++j){
      int jj = 2 * j + l5;
      int jjc = (jj < cnt) ? jj : 0;
      int sj = __shfl(srcj, jjc, 64);
      if (jj < cnt){
        float eh = exs[wid][(jj << 2) + h];
        const float4 v = *(const float4*)&vcat[(size_t)sj * VC1 + c4];
        a0 = fmaf(eh, v.x, a0); a1 = fmaf(eh, v.y, a1);
        a2 = fmaf(eh, v.z, a2); a3 = fmaf(eh, v.w, a3);
      }
    }
    __builtin_amdgcn_wave_barrier();
  }
  a0 += __shfl_xor(a0, 32, 64); a1 += __shfl_xor(a1, 32, 64);
  a2 += __shfl_xor(a2, 32, 64); a3 += __shfl_xor(a3, 32, 64);
  s0 = wave_sum(s0); s1 = wave_sum(s1); s2 = wave_sum(s2); s3 = wave_sum(s3);
  float sh = (h == 0) ? s0 : (h == 1) ? s1 : (h == 2) ? s2 : s3;
  sh = fmaxf(sh, 1e-16f);
  float inv = 1.f / sh;
  const float4 r = *(const float4*)&hres[(size_t)n * HIDDEN + c4];
  float v0 = a0 * inv + r.x, v1 = a1 * inv + r.y;
  float v2 = a2 * inv + r.z, v3 = a3 * inv + r.w;
  float mean = wave_sum(v0 + v1 + v2 + v3) * (1.f / 256.f);
  float d0 = v0 - mean, d1 = v1 - mean, d2 = v2 - mean, d3 = v3 - mean;
  float var = wave_sum(d0*d0 + d1*d1 + d2*d2 + d3*d3) * (1.f / 256.f);
  float rs = rsqrtf(var + LN_EPS);
  const float4 g4 = *(const float4*)&g[c4];
  const float4 b4 = *(const float4*)&beta[c4];
  if (l5 == 0){
    float4 o;
    o.x = fmaxf(d0 * rs * g4.x + b4.x, 0.f);
    o.y = fmaxf(d1 * rs * g4.y + b4.y, 0.f);
    o.z = fmaxf(d2 * rs * g4.z + b4.z, 0.f);
    o.w = fmaxf(d3 * rs * g4.w + b4.w, 0.f);
    *(float4*)&out[(size_t)n * HIDDEN + c4] = o;
  }
}

// ---------------- layer 1 aggregation: u[n][h*128+c] = 0.25/s_h * sum_j a[e,h]*h2[j][c]
__global__ __launch_bounds__(256) void gat1_agg(const float* __restrict__ h2,
    const float* __restrict__ ak2,
    const int* __restrict__ row_ptr, const int* __restrict__ col_idx,
    float* __restrict__ u){
  __shared__ float exs[4][256];
  int wid = threadIdx.x >> 6;
  int lane = threadIdx.x & 63;
  int n = blockIdx.x * 4 + wid;
  if (n >= N_NODES) return;
  int start = row_ptr[n], end = row_ptr[n + 1];
  float m0 = -1e30f, m1 = -1e30f, m2 = -1e30f, m3 = -1e30f;
  for (int e = start + lane; e < end; e += 64){
    const float4 a = *(const float4*)&ak2[(size_t)col_idx[e] * 4];
    m0 = fmaxf(m0, a.x); m1 = fmaxf(m1, a.y);
    m2 = fmaxf(m2, a.z); m3 = fmaxf(m3, a.w);
  }
  m0 = wave_max(m0); m1 = wave_max(m1); m2 = wave_max(m2); m3 = wave_max(m3);
  int l5 = lane >> 5;                 // half-wave id (edge parity)
  int c4 = (lane & 31) << 2;          // my 4 channels of h2
  float acc[4][4] = {{0.f}};          // [head][chan]
  float s0 = 0.f, s1 = 0.f, s2 = 0.f, s3 = 0.f;
  for (int base = start; base < end; base += 64){
    int e = base + lane;
    float4 ex = make_float4(0.f, 0.f, 0.f, 0.f);
    int srcj = 0;
    if (e < end){
      srcj = col_idx[e];
      const float4 a = *(const float4*)&ak2[(size_t)srcj * 4];
      ex.x = __expf(a.x - m0); ex.y = __expf(a.y - m1);
      ex.z = __expf(a.z - m2); ex.w = __expf(a.w - m3);
      s0 += ex.x; s1 += ex.y; s2 += ex.z; s3 += ex.w;
    }
    *(float4*)&exs[wid][lane << 2] = ex;
    __builtin_amdgcn_wave_barrier();
    int cnt = end - base; if (cnt > 64) cnt = 64;
    int half = (cnt + 1) >> 1;
    for (int j = 0; j < half; ++j){
      int jj = 2 * j + l5;
      int jjc = (jj < cnt) ? jj : 0;
      int sj = __shfl(srcj, jjc, 64);
      if (jj < cnt){
        const float4 eh = *(const float4*)&exs[wid][jj << 2];
        const float4 v = *(const float4*)&h2[(size_t)sj * 128 + c4];
        acc[0][0] = fmaf(eh.x, v.x, acc[0][0]); acc[0][1] = fmaf(eh.x, v.y, acc[0][1]);
        acc[0][2] = fmaf(eh.x, v.z, acc[0][2]); acc[0][3] = fmaf(eh.x, v.w, acc[0][3]);
        acc[1][0] = fmaf(eh.y, v.x, acc[1][0]); acc[1][1] = fmaf(eh.y, v.y, acc[1][1]);
        acc[1][2] = fmaf(eh.y, v.z, acc[1][2]); acc[1][3] = fmaf(eh.y, v.w, acc[1][3]);
        acc[2][0] = fmaf(eh.z, v.x, acc[2][0]); acc[2][1] = fmaf(eh.z, v.y, acc[2][1]);
        acc[2][2] = fmaf(eh.z, v.z, acc[2][2]); acc[2][3] = fmaf(eh.z, v.w, acc[2][3]);
        acc[3][0] = fmaf(eh.w, v.x, acc[3][0]); acc[3][1] = fmaf(eh.w, v.y, acc[3][1]);
        acc[3][2] = fmaf(eh.w, v.z, acc[3][2]); acc[3][3] = fmaf(eh.w, v.w, acc[3][3]);
      }
    }
    __builtin_amdgcn_wave_barrier();
  }
#pragma unroll
  for (int h = 0; h < 4; h++)
#pragma unroll
    for (int c = 0; c < 4; c++)
      acc[h][c] += __shfl_xor(acc[h][c], 32, 64);
  s0 = wave_sum(s0); s1 = wave_sum(s1); s2 = wave_sum(s2); s3 = wave_sum(s3);
  float w0 = 0.25f / fmaxf(s0, 1e-16f);
  float w1 = 0.25f / fmaxf(s1, 1e-16f);
  float w2 = 0.25f / fmaxf(s2, 1e-16f);
  float w3 = 0.25f / fmaxf(s3, 1e-16f);
  if (l5 == 0){
    float* ur = &u[(size_t)n * 512 + c4];
    *(float4*)(ur)       = make_float4(acc[0][0]*w0, acc[0][1]*w0, acc[0][2]*w0, acc[0][3]*w0);
    *(float4*)(ur + 128) = make_float4(acc[1][0]*w1, acc[1][1]*w1, acc[1][2]*w1, acc[1][3]*w1);
    *(float4*)(ur + 256) = make_float4(acc[2][0]*w2, acc[2][1]*w2, acc[2][2]*w2, acc[2][3]*w2);
    *(float4*)(ur + 384) = make_float4(acc[3][0]*w3, acc[3][1]*w3, acc[3][2]*w3, acc[3][3]*w3);
  }
}

// ---------------- partial-sum + bias + residual + LN (in place over h2) ------------
__global__ __launch_bounds__(256) void ln_res4(const float* __restrict__ p0,
    const float* __restrict__ p1, const float* __restrict__ mb,
    const float* hres, const float* __restrict__ g,
    const float* __restrict__ beta, float* out){
  int wid = threadIdx.x >> 6, lane = threadIdx.x & 63;
  int n = blockIdx.x * 4 + wid;
  if (n >= N_NODES) return;
  int c2 = lane << 1;
  float2 q0 = *(const float2*)&p0[(size_t)n * 128 + c2];
  float2 q1 = *(const float2*)&p1[(size_t)n * 128 + c2];
  float2 m2 = *(const float2*)&mb[c2];
  float2 r  = *(const float2*)&hres[(size_t)n * 128 + c2];
  float vx = q0.x + q1.x + m2.x + r.x;
  float vy = q0.y + q1.y + m2.y + r.y;
  float mean = wave_sum(vx + vy) * (1.f / 128.f);
  float dx = vx - mean, dy = vy - mean;
  float var = wave_sum(dx * dx + dy * dy) * (1.f / 128.f);
  float rs = rsqrtf(var + LN_EPS);
  float2 gg = *(const float2*)&g[c2];
  float2 bb = *(const float2*)&beta[c2];
  *(float2*)&out[(size_t)n * 128 + c2] =
      make_float2(dx * rs * gg.x + bb.x, dy * rs * gg.y + bb.y);
}

// ---------------- launch ----------------
extern "C" void kernel_launch(void* const* d_in, const int* in_sizes, int n_in,
                              void* d_out, int out_size, void* d_ws, size_t ws_size,
                              hipStream_t stream) {
  const float* x     = (const float*)d_in[0];
  const int*   ei    = (const int*)  d_in[1];   // int32 or int64 -- detected on device
  const float* W_in  = (const float*)d_in[2];
  const float* b_in  = (const float*)d_in[3];
  const float* Wk1   = (const float*)d_in[6];
  const float* Wv1   = (const float*)d_in[8];
  const float* bv1   = (const float*)d_in[9];
  const float* att1  = (const float*)d_in[10];
  const float* g1    = (const float*)d_in[11];
  const float* beta1 = (const float*)d_in[12];
  const float* Wk2   = (const float*)d_in[15];
  const float* Wv2   = (const float*)d_in[17];
  const float* bv2   = (const float*)d_in[18];
  const float* att2  = (const float*)d_in[19];
  const float* g2    = (const float*)d_in[20];
  const float* beta2 = (const float*)d_in[21];
  const float* W_out = (const float*)d_in[22];
  const float* b_out = (const float*)d_in[23];
  float* zout = (float*)d_out;

  char* base = (char*)d_ws;
  size_t off = 0;
  auto take = [&](size_t bytes) -> void* {
    void* p = base + off;
    off += (bytes + 255) & ~(size_t)255;
    return p;
  };
  float* h1      = (float*)take((size_t)N_NODES * 128 * 4);  // dead after gat0 -> p0
  float* h2      = (float*)take((size_t)N_NODES * 128 * 4);  // LN'd in place (h3)
  float* u       = (float*)take((size_t)N_NODES * 512 * 4);  // vcat1 aliases (dead before)
  float* vcat1   = u;
  float* p1buf   = (float*)take((size_t)N_NODES * 128 * 4);  // K-split partial plane 1
  float* ak2     = (float*)take((size_t)N_NODES * 4 * 4);
  float* Wka1    = (float*)take(128 * NH * 4);
  float* Wka2    = (float*)take(128 * NH * 4);
  float* W2r     = (float*)take(512 * 128 * 4);
  float* mb      = (float*)take(128 * 4);
  int*   counts  = (int*)take((size_t)N_NODES * 4);
  int*   row_ptr = (int*)take((size_t)(N_NODES + 1) * 4);
  int*   fillp   = (int*)take((size_t)N_NODES * 4);
  int*   col_idx = (int*)take((size_t)N_EDGES * 4);
  int*   eflag   = (int*)take(256);
  float* p0buf   = h1;      // h1 dead after gat0 consumes it
  float* h3      = h2;      // ln_res4 is in-place safe

  const int RT = (N_NODES + 63) / 64;   // 313 row tiles

  // CSR build
  hipMemsetAsync(counts, 0, (size_t)N_NODES * 4, stream);
  detect_kernel<<<1, 1024, 0, stream>>>(ei, eflag);
  hist_kernel<<<512, 256, 0, stream>>>(ei, eflag, counts);
  scan_kernel<<<1, 1024, 0, stream>>>(counts, row_ptr, fillp);
  scatter_kernel<<<512, 256, 0, stream>>>(ei, eflag, fillp, col_idx);

  prep_ak_weights<<<2, 256, 0, stream>>>(Wk1, att1, Wk2, att2, Wka1, Wka2);
  prep_w2r<<<64, 256, 0, stream>>>(Wv2, bv2, W2r, mb);

  // h1 = relu(x @ W_in + b_in)
  gemm_sb<1, 128><<<dim3(RT, 2), 256, 0, stream>>>(x, W_in, b_in, h1, 128, 128);
  // vcat1 v-part = h1 @ Wv1 + bv1 ; ak-part = h1 @ Wka1
  gemm_sb<0, 128><<<dim3(RT, 2), 256, 0, stream>>>(h1, Wv1, bv1, vcat1, 128, VC1);
  akgemv<<<(N_NODES + 3) / 4, 256, 0, stream>>>(h1, Wka1, vcat1, 128, VC1);
  // layer 0 aggregation + residual + LN + relu -> h2
  gat0<<<N_NODES / 4, 256, 0, stream>>>(vcat1, row_ptr, col_idx, h1, g1, beta1, h2);
  // layer 1: ak2 then aggregated features u (projection deferred)
  akgemv<<<(N_NODES + 3) / 4, 256, 0, stream>>>(h2, Wka2, ak2, 0, 4);
  gat1_agg<<<N_NODES / 4, 256, 0, stream>>>(h2, ak2, row_ptr, col_idx, u);
  // o2 partials: p0 + p1 = u @ W2r   (2-way K-split for 2x waves/CU)
  gemm_ks<<<dim3(RT, 2, 2), 256, 0, stream>>>(u, W2r, p0buf, p1buf);
  // h3 = LN(p0 + p1 + mb + h2) * g2 + beta2   (in place over h2)
  ln_res4<<<N_NODES / 4, 256, 0, stream>>>(p0buf, p1buf, mb, h2, g2, beta2, h3);
  // z = h3 @ W_out + b_out
  gemm_sb<0, 128><<<dim3(RT, 2), 256, 0, stream>>>(h3, W_out, b_out, zout, 128, 128);
}

// Round 11
// 347.094 us; speedup vs baseline: 1.3103x; 1.0398x over previous
//
#include <hip/hip_runtime.h>
#include <hip/hip_bf16.h>
#include <math.h>

// Problem constants (fixed by the reference)
#define N_NODES 20000
#define N_EDGES 320000
#define DIM     128
#define HIDDEN  128
#define NH      4
#define C1      32
#define C2      128
#define VC1     132   // 128 v | 4 ak   (query term cancels in softmax)
#define LN_EPS  1e-5f

// ---------------- wave helpers ----------------
__device__ __forceinline__ float wave_sum(float v){
#pragma unroll
  for (int o = 32; o; o >>= 1) v += __shfl_xor(v, o, 64);
  return v;
}
__device__ __forceinline__ float wave_max(float v){
#pragma unroll
  for (int o = 32; o; o >>= 1) v = fmaxf(v, __shfl_xor(v, o, 64));
  return v;
}

// ---------------- edge_index dtype detect ----------------
__global__ __launch_bounds__(1024) void detect_kernel(const int* __restrict__ ei32,
                                                      int* __restrict__ flag){
  __shared__ int any;
  if (threadIdx.x == 0) any = 0;
  __syncthreads();
  if (ei32[2 * threadIdx.x + 1] != 0) atomicOr(&any, 1);
  __syncthreads();
  if (threadIdx.x == 0) *flag = (any == 0) ? 1 : 0;
}

// ---------------- CSR build ----------------
__global__ void hist_kernel(const int* __restrict__ ei, const int* __restrict__ flag,
                            int* __restrict__ counts){
  const bool wide = (*flag != 0);
  for (int e = blockIdx.x * blockDim.x + threadIdx.x; e < N_EDGES;
       e += gridDim.x * blockDim.x){
    int d = wide ? ei[2 * (N_EDGES + e)] : ei[N_EDGES + e];   // dst row
    atomicAdd(&counts[d], 1);
  }
}

__global__ __launch_bounds__(1024) void scan_kernel(const int* __restrict__ counts,
    int* __restrict__ row_ptr, int* __restrict__ fill_ptr){
  const int PER = 20;                 // 1024*20 = 20480 >= 20000
  int t = threadIdx.x;
  int base = t * PER;
  int local[PER];
  int s = 0;
#pragma unroll
  for (int i = 0; i < PER; i++){
    int idx = base + i;
    int c = (idx < N_NODES) ? counts[idx] : 0;
    s += c; local[i] = s;             // inclusive within thread
  }
  __shared__ int bs[1024];
  bs[t] = s; __syncthreads();
  for (int off = 1; off < 1024; off <<= 1){
    int v = (t >= off) ? bs[t - off] : 0;
    __syncthreads();
    bs[t] += v;
    __syncthreads();
  }
  int excl = bs[t] - s;
  int prev = 0;
#pragma unroll
  for (int i = 0; i < PER; i++){
    int idx = base + i;
    if (idx < N_NODES){
      row_ptr[idx + 1] = excl + local[i];
      fill_ptr[idx]    = excl + prev;
    }
    prev = local[i];
  }
  if (t == 0) row_ptr[0] = 0;
}

__global__ void scatter_kernel(const int* __restrict__ ei, const int* __restrict__ flag,
                               int* __restrict__ fill_ptr, int* __restrict__ col_idx){
  const bool wide = (*flag != 0);
  for (int e = blockIdx.x * blockDim.x + threadIdx.x; e < N_EDGES;
       e += gridDim.x * blockDim.x){
    int d = wide ? ei[2 * (N_EDGES + e)] : ei[N_EDGES + e];
    int s = wide ? ei[2 * e]             : ei[e];
    int pos = atomicAdd(&fill_ptr[d], 1);
    col_idx[pos] = s;
  }
}

// ---------------- ak weight fold: Wka[k][h] = sum_c Wk[k][h*C+c]*att[h][C+c] ------
// (bk bias dropped: a per-head constant shift cancels in segment softmax)
__global__ void prep_ak_weights(const float* __restrict__ Wk1, const float* __restrict__ att1,
                                const float* __restrict__ Wk2, const float* __restrict__ att2,
                                float* __restrict__ Wka1, float* __restrict__ Wka2){
  int tid = blockIdx.x * blockDim.x + threadIdx.x;
  int stride = gridDim.x * blockDim.x;
  for (int idx = tid; idx < 128 * NH; idx += stride){
    int k = idx >> 2, h = idx & 3;
    float s = 0.f;
    for (int c = 0; c < C1; c++)
      s += Wk1[k * 128 + h * C1 + c] * att1[h * 2 * C1 + C1 + c];
    Wka1[idx] = s;
  }
  for (int idx = tid; idx < 128 * NH; idx += stride){
    int k = idx >> 2, h = idx & 3;
    float s = 0.f;
    for (int c = 0; c < C2; c++)
      s += Wk2[k * 512 + h * C2 + c] * att2[h * 2 * C2 + C2 + c];
    Wka2[idx] = s;
  }
}

// ---------------- W2r[h*128+k][c] = Wv2[k][h*128+c]; mb[c] = 0.25*sum_h bv2[h*128+c]
__global__ void prep_w2r(const float* __restrict__ Wv2, const float* __restrict__ bv2,
                         float* __restrict__ W2r, float* __restrict__ mb){
  int tid = blockIdx.x * blockDim.x + threadIdx.x;
  if (tid < 16384){
    int hk = tid >> 5;          // 0..511
    int c4 = (tid & 31) << 2;   // 0..124
    int h = hk >> 7, k = hk & 127;
    *(float4*)&W2r[(size_t)hk * 128 + c4] =
        *(const float4*)&Wv2[(size_t)k * 512 + h * 128 + c4];
  }
  if (tid < 32){
    int c4 = tid << 2;
    float4 b0 = *(const float4*)&bv2[c4];
    float4 b1 = *(const float4*)&bv2[128 + c4];
    float4 b2 = *(const float4*)&bv2[256 + c4];
    float4 b3 = *(const float4*)&bv2[384 + c4];
    *(float4*)&mb[c4] = make_float4(0.25f * (b0.x + b1.x + b2.x + b3.x),
                                    0.25f * (b0.y + b1.y + b2.y + b3.y),
                                    0.25f * (b0.z + b1.z + b2.z + b3.z),
                                    0.25f * (b0.w + b1.w + b2.w + b3.w));
  }
}

// ---------------- akgemv: dst[n][V+h] = sum_k hin[n][k] * Wka[k][h] ----------------
__global__ __launch_bounds__(256) void akgemv(const float* __restrict__ hin,
    const float* __restrict__ Wka, float* __restrict__ dst, int V, int VC){
  int wid = threadIdx.x >> 6, lane = threadIdx.x & 63;
  int n = blockIdx.x * 4 + wid;
  if (n >= N_NODES) return;
  float2 hv = *(const float2*)&hin[(size_t)n * 128 + (lane << 1)];
  float4 wa = *(const float4*)&Wka[lane << 3];
  float4 wb = *(const float4*)&Wka[(lane << 3) + 4];
  float p0 = hv.x * wa.x + hv.y * wb.x;
  float p1 = hv.x * wa.y + hv.y * wb.y;
  float p2 = hv.x * wa.z + hv.y * wb.z;
  float p3 = hv.x * wa.w + hv.y * wb.w;
  p0 = wave_sum(p0); p1 = wave_sum(p1); p2 = wave_sum(p2); p3 = wave_sum(p3);
  if (lane == 0)
    *(float4*)&dst[(size_t)n * VC + V] = make_float4(p0, p1, p2, p3);
}

// ---------------- scalar-broadcast f32 GEMM (no LDS) — round-8 verified body ------
// Wave layout: lane = row (64 rows/wave), 16 wave-uniform cols per wave
// (4 waves/block -> 64-col tile). Per k: 1 cached X dword/lane + 4 uniform
// float4 W loads (SGPR via readfirstlane) + 16 FMA. 16 VGPR, no barriers.
template <int ACT, int K>  // ACT: 0 = none, 1 = relu
__global__ __launch_bounds__(256) void gemm_sb(const float* __restrict__ X,
    const float* __restrict__ W, const float* __restrict__ bias,
    float* __restrict__ Y, int M, int ldY){
  const int lane = threadIdx.x & 63;
  const int col0 = __builtin_amdgcn_readfirstlane(
      blockIdx.y * 64 + ((threadIdx.x >> 6) << 4));
  const int row = blockIdx.x * 64 + lane;
  int rclamp = row < N_NODES ? row : N_NODES - 1;
  const float* xr = X + (size_t)rclamp * K;
  float acc[16];
#pragma unroll
  for (int c = 0; c < 16; c++) acc[c] = 0.f;
#pragma unroll 4
  for (int k = 0; k < K; ++k){
    float xv = xr[k];
    const float* wr = W + (size_t)k * M + col0;
    float4 wa = *(const float4*)(wr);
    float4 wb = *(const float4*)(wr + 4);
    float4 wc = *(const float4*)(wr + 8);
    float4 wd = *(const float4*)(wr + 12);
    acc[0]  = fmaf(xv, wa.x, acc[0]);  acc[1]  = fmaf(xv, wa.y, acc[1]);
    acc[2]  = fmaf(xv, wa.z, acc[2]);  acc[3]  = fmaf(xv, wa.w, acc[3]);
    acc[4]  = fmaf(xv, wb.x, acc[4]);  acc[5]  = fmaf(xv, wb.y, acc[5]);
    acc[6]  = fmaf(xv, wb.z, acc[6]);  acc[7]  = fmaf(xv, wb.w, acc[7]);
    acc[8]  = fmaf(xv, wc.x, acc[8]);  acc[9]  = fmaf(xv, wc.y, acc[9]);
    acc[10] = fmaf(xv, wc.z, acc[10]); acc[11] = fmaf(xv, wc.w, acc[11]);
    acc[12] = fmaf(xv, wd.x, acc[12]); acc[13] = fmaf(xv, wd.y, acc[13]);
    acc[14] = fmaf(xv, wd.z, acc[14]); acc[15] = fmaf(xv, wd.w, acc[15]);
  }
  if (row < N_NODES){
    float* yr = Y + (size_t)row * ldY + col0;
#pragma unroll
    for (int j = 0; j < 4; j++){
      float4 b4 = *(const float4*)&bias[col0 + 4 * j];
      float4 o;
      o.x = acc[4*j]     + b4.x; o.y = acc[4*j + 1] + b4.y;
      o.z = acc[4*j + 2] + b4.z; o.w = acc[4*j + 3] + b4.w;
      if (ACT == 1){
        o.x = fmaxf(o.x, 0.f); o.y = fmaxf(o.y, 0.f);
        o.z = fmaxf(o.z, 0.f); o.w = fmaxf(o.w, 0.f);
      }
      *(float4*)(yr + 4 * j) = o;
    }
  }
}

// ---------------- K-split GEMM for o2 with LDS-staged X ----------------------------
// K=512 in 2 splits of 256 k (blockIdx.z). X staged cooperatively in 64-row x
// 64-k LDS chunks (pad 65 -> (r+k)%32 banks, 2-way = free). Compute reads one
// ds_read_b32 per k; W stays on the scalar path (uniform col0). Bulk staging
// decouples HBM latency from the FMA chain.
__global__ __launch_bounds__(256) void gemm_ks(const float* __restrict__ X,
    const float* __restrict__ W, float* __restrict__ P0, float* __restrict__ P1){
  __shared__ float Xs[64 * 65];       // 16.6 KB
  const int t = threadIdx.x;
  const int lane = t & 63;
  const int col0 = __builtin_amdgcn_readfirstlane(
      blockIdx.y * 64 + ((t >> 6) << 4));
  const int kb0 = __builtin_amdgcn_readfirstlane(blockIdx.z * 256);
  const int row0 = blockIdx.x * 64;
  float acc[16];
#pragma unroll
  for (int c = 0; c < 16; c++) acc[c] = 0.f;
  for (int kc = 0; kc < 256; kc += 64){
    const int kb = kb0 + kc;
    if (kc) __syncthreads();          // protect Xs before overwrite
    // stage 64 rows x 64 k: 1024 float4s, 4 per thread, coalesced 256B segments
#pragma unroll
    for (int i = 0; i < 4; i++){
      int idx4 = t + i * 256;         // [0,1024)
      int r = idx4 >> 4;              // 0..63
      int c4 = (idx4 & 15) << 2;      // 0..60
      int grow = row0 + r; if (grow >= N_NODES) grow = N_NODES - 1;
      float4 v = *(const float4*)&X[(size_t)grow * 512 + kb + c4];
      float* d = &Xs[r * 65 + c4];
      d[0] = v.x; d[1] = v.y; d[2] = v.z; d[3] = v.w;
    }
    __syncthreads();
    const float* xl = &Xs[lane * 65];
#pragma unroll 4
    for (int k = 0; k < 64; ++k){
      float xv = xl[k];
      const float* wr = W + (size_t)(kb + k) * 128 + col0;
      float4 wa = *(const float4*)(wr);
      float4 wb = *(const float4*)(wr + 4);
      float4 wc = *(const float4*)(wr + 8);
      float4 wd = *(const float4*)(wr + 12);
      acc[0]  = fmaf(xv, wa.x, acc[0]);  acc[1]  = fmaf(xv, wa.y, acc[1]);
      acc[2]  = fmaf(xv, wa.z, acc[2]);  acc[3]  = fmaf(xv, wa.w, acc[3]);
      acc[4]  = fmaf(xv, wb.x, acc[4]);  acc[5]  = fmaf(xv, wb.y, acc[5]);
      acc[6]  = fmaf(xv, wb.z, acc[6]);  acc[7]  = fmaf(xv, wb.w, acc[7]);
      acc[8]  = fmaf(xv, wc.x, acc[8]);  acc[9]  = fmaf(xv, wc.y, acc[9]);
      acc[10] = fmaf(xv, wc.z, acc[10]); acc[11] = fmaf(xv, wc.w, acc[11]);
      acc[12] = fmaf(xv, wd.x, acc[12]); acc[13] = fmaf(xv, wd.y, acc[13]);
      acc[14] = fmaf(xv, wd.z, acc[14]); acc[15] = fmaf(xv, wd.w, acc[15]);
    }
  }
  const int row = row0 + lane;
  if (row < N_NODES){
    float* P = blockIdx.z ? P1 : P0;
    float* yr = P + (size_t)row * 128 + col0;
#pragma unroll
    for (int j = 0; j < 4; j++)
      *(float4*)(yr + 4 * j) = make_float4(acc[4*j], acc[4*j+1], acc[4*j+2], acc[4*j+3]);
  }
}

// ---------------- layer 0: GAT (concat heads) + residual + LN + relu ----------------
__global__ __launch_bounds__(256) void gat0(const float* __restrict__ vcat,
    const int* __restrict__ row_ptr, const int* __restrict__ col_idx,
    const float* __restrict__ hres, const float* __restrict__ g,
    const float* __restrict__ beta, float* __restrict__ out){
  __shared__ float exs[4][256];
  int wid = threadIdx.x >> 6;
  int lane = threadIdx.x & 63;
  int n = blockIdx.x * 4 + wid;
  if (n >= N_NODES) return;
  int start = row_ptr[n], end = row_ptr[n + 1];
  float m0 = -1e30f, m1 = -1e30f, m2 = -1e30f, m3 = -1e30f;
  for (int e = start + lane; e < end; e += 64){
    int s = col_idx[e];
    const float4 ak = *(const float4*)&vcat[(size_t)s * VC1 + 128];
    m0 = fmaxf(m0, ak.x); m1 = fmaxf(m1, ak.y);
    m2 = fmaxf(m2, ak.z); m3 = fmaxf(m3, ak.w);
  }
  m0 = wave_max(m0); m1 = wave_max(m1); m2 = wave_max(m2); m3 = wave_max(m3);
  int l5 = lane >> 5;                 // half-wave id (edge parity)
  int c4 = (lane & 31) << 2;          // my 4 channels
  int h  = (lane & 31) >> 3;          // their head
  float a0 = 0.f, a1 = 0.f, a2 = 0.f, a3 = 0.f;
  float s0 = 0.f, s1 = 0.f, s2 = 0.f, s3 = 0.f;
  for (int base = start; base < end; base += 64){
    int e = base + lane;
    float4 ex = make_float4(0.f, 0.f, 0.f, 0.f);
    int srcj = 0;
    if (e < end){
      srcj = col_idx[e];
      const float4 ak = *(const float4*)&vcat[(size_t)srcj * VC1 + 128];
      ex.x = __expf(ak.x - m0); ex.y = __expf(ak.y - m1);
      ex.z = __expf(ak.z - m2); ex.w = __expf(ak.w - m3);
      s0 += ex.x; s1 += ex.y; s2 += ex.z; s3 += ex.w;
    }
    *(float4*)&exs[wid][lane << 2] = ex;
    __builtin_amdgcn_wave_barrier();
    int cnt = end - base; if (cnt > 64) cnt = 64;
    int half = (cnt + 1) >> 1;
    for (int j = 0; j < half; ++j){
      int jj = 2 * j + l5;
      int jjc = (jj < cnt) ? jj : 0;
      int sj = __shfl(srcj, jjc, 64);
      if (jj < cnt){
        float eh = exs[wid][(jj << 2) + h];
        const float4 v = *(const float4*)&vcat[(size_t)sj * VC1 + c4];
        a0 = fmaf(eh, v.x, a0); a1 = fmaf(eh, v.y, a1);
        a2 = fmaf(eh, v.z, a2); a3 = fmaf(eh, v.w, a3);
      }
    }
    __builtin_amdgcn_wave_barrier();
  }
  a0 += __shfl_xor(a0, 32, 64); a1 += __shfl_xor(a1, 32, 64);
  a2 += __shfl_xor(a2, 32, 64); a3 += __shfl_xor(a3, 32, 64);
  s0 = wave_sum(s0); s1 = wave_sum(s1); s2 = wave_sum(s2); s3 = wave_sum(s3);
  float sh = (h == 0) ? s0 : (h == 1) ? s1 : (h == 2) ? s2 : s3;
  sh = fmaxf(sh, 1e-16f);
  float inv = 1.f / sh;
  const float4 r = *(const float4*)&hres[(size_t)n * HIDDEN + c4];
  float v0 = a0 * inv + r.x, v1 = a1 * inv + r.y;
  float v2 = a2 * inv + r.z, v3 = a3 * inv + r.w;
  float mean = wave_sum(v0 + v1 + v2 + v3) * (1.f / 256.f);
  float d0 = v0 - mean, d1 = v1 - mean, d2 = v2 - mean, d3 = v3 - mean;
  float var = wave_sum(d0*d0 + d1*d1 + d2*d2 + d3*d3) * (1.f / 256.f);
  float rs = rsqrtf(var + LN_EPS);
  const float4 g4 = *(const float4*)&g[c4];
  const float4 b4 = *(const float4*)&beta[c4];
  if (l5 == 0){
    float4 o;
    o.x = fmaxf(d0 * rs * g4.x + b4.x, 0.f);
    o.y = fmaxf(d1 * rs * g4.y + b4.y, 0.f);
    o.z = fmaxf(d2 * rs * g4.z + b4.z, 0.f);
    o.w = fmaxf(d3 * rs * g4.w + b4.w, 0.f);
    *(float4*)&out[(size_t)n * HIDDEN + c4] = o;
  }
}

// ---------------- layer 1 aggregation: u[n][h*128+c] = 0.25/s_h * sum_j a[e,h]*h2[j][c]
__global__ __launch_bounds__(256) void gat1_agg(const float* __restrict__ h2,
    const float* __restrict__ ak2,
    const int* __restrict__ row_ptr, const int* __restrict__ col_idx,
    float* __restrict__ u){
  __shared__ float exs[4][256];
  int wid = threadIdx.x >> 6;
  int lane = threadIdx.x & 63;
  int n = blockIdx.x * 4 + wid;
  if (n >= N_NODES) return;
  int start = row_ptr[n], end = row_ptr[n + 1];
  float m0 = -1e30f, m1 = -1e30f, m2 = -1e30f, m3 = -1e30f;
  for (int e = start + lane; e < end; e += 64){
    const float4 a = *(const float4*)&ak2[(size_t)col_idx[e] * 4];
    m0 = fmaxf(m0, a.x); m1 = fmaxf(m1, a.y);
    m2 = fmaxf(m2, a.z); m3 = fmaxf(m3, a.w);
  }
  m0 = wave_max(m0); m1 = wave_max(m1); m2 = wave_max(m2); m3 = wave_max(m3);
  int l5 = lane >> 5;                 // half-wave id (edge parity)
  int c4 = (lane & 31) << 2;          // my 4 channels of h2
  float acc[4][4] = {{0.f}};          // [head][chan]
  float s0 = 0.f, s1 = 0.f, s2 = 0.f, s3 = 0.f;
  for (int base = start; base < end; base += 64){
    int e = base + lane;
    float4 ex = make_float4(0.f, 0.f, 0.f, 0.f);
    int srcj = 0;
    if (e < end){
      srcj = col_idx[e];
      const float4 a = *(const float4*)&ak2[(size_t)srcj * 4];
      ex.x = __expf(a.x - m0); ex.y = __expf(a.y - m1);
      ex.z = __expf(a.z - m2); ex.w = __expf(a.w - m3);
      s0 += ex.x; s1 += ex.y; s2 += ex.z; s3 += ex.w;
    }
    *(float4*)&exs[wid][lane << 2] = ex;
    __builtin_amdgcn_wave_barrier();
    int cnt = end - base; if (cnt > 64) cnt = 64;
    int half = (cnt + 1) >> 1;
    for (int j = 0; j < half; ++j){
      int jj = 2 * j + l5;
      int jjc = (jj < cnt) ? jj : 0;
      int sj = __shfl(srcj, jjc, 64);
      if (jj < cnt){
        const float4 eh = *(const float4*)&exs[wid][jj << 2];
        const float4 v = *(const float4*)&h2[(size_t)sj * 128 + c4];
        acc[0][0] = fmaf(eh.x, v.x, acc[0][0]); acc[0][1] = fmaf(eh.x, v.y, acc[0][1]);
        acc[0][2] = fmaf(eh.x, v.z, acc[0][2]); acc[0][3] = fmaf(eh.x, v.w, acc[0][3]);
        acc[1][0] = fmaf(eh.y, v.x, acc[1][0]); acc[1][1] = fmaf(eh.y, v.y, acc[1][1]);
        acc[1][2] = fmaf(eh.y, v.z, acc[1][2]); acc[1][3] = fmaf(eh.y, v.w, acc[1][3]);
        acc[2][0] = fmaf(eh.z, v.x, acc[2][0]); acc[2][1] = fmaf(eh.z, v.y, acc[2][1]);
        acc[2][2] = fmaf(eh.z, v.z, acc[2][2]); acc[2][3] = fmaf(eh.z, v.w, acc[2][3]);
        acc[3][0] = fmaf(eh.w, v.x, acc[3][0]); acc[3][1] = fmaf(eh.w, v.y, acc[3][1]);
        acc[3][2] = fmaf(eh.w, v.z, acc[3][2]); acc[3][3] = fmaf(eh.w, v.w, acc[3][3]);
      }
    }
    __builtin_amdgcn_wave_barrier();
  }
#pragma unroll
  for (int h = 0; h < 4; h++)
#pragma unroll
    for (int c = 0; c < 4; c++)
      acc[h][c] += __shfl_xor(acc[h][c], 32, 64);
  s0 = wave_sum(s0); s1 = wave_sum(s1); s2 = wave_sum(s2); s3 = wave_sum(s3);
  float w0 = 0.25f / fmaxf(s0, 1e-16f);
  float w1 = 0.25f / fmaxf(s1, 1e-16f);
  float w2 = 0.25f / fmaxf(s2, 1e-16f);
  float w3 = 0.25f / fmaxf(s3, 1e-16f);
  if (l5 == 0){
    float* ur = &u[(size_t)n * 512 + c4];
    *(float4*)(ur)       = make_float4(acc[0][0]*w0, acc[0][1]*w0, acc[0][2]*w0, acc[0][3]*w0);
    *(float4*)(ur + 128) = make_float4(acc[1][0]*w1, acc[1][1]*w1, acc[1][2]*w1, acc[1][3]*w1);
    *(float4*)(ur + 256) = make_float4(acc[2][0]*w2, acc[2][1]*w2, acc[2][2]*w2, acc[2][3]*w2);
    *(float4*)(ur + 384) = make_float4(acc[3][0]*w3, acc[3][1]*w3, acc[3][2]*w3, acc[3][3]*w3);
  }
}

// ---------------- partial-sum + bias + residual + LN (in place over h2) ------------
__global__ __launch_bounds__(256) void ln_res4(const float* __restrict__ p0,
    const float* __restrict__ p1, const float* __restrict__ mb,
    const float* hres, const float* __restrict__ g,
    const float* __restrict__ beta, float* out){
  int wid = threadIdx.x >> 6, lane = threadIdx.x & 63;
  int n = blockIdx.x * 4 + wid;
  if (n >= N_NODES) return;
  int c2 = lane << 1;
  float2 q0 = *(const float2*)&p0[(size_t)n * 128 + c2];
  float2 q1 = *(const float2*)&p1[(size_t)n * 128 + c2];
  float2 m2 = *(const float2*)&mb[c2];
  float2 r  = *(const float2*)&hres[(size_t)n * 128 + c2];
  float vx = q0.x + q1.x + m2.x + r.x;
  float vy = q0.y + q1.y + m2.y + r.y;
  float mean = wave_sum(vx + vy) * (1.f / 128.f);
  float dx = vx - mean, dy = vy - mean;
  float var = wave_sum(dx * dx + dy * dy) * (1.f / 128.f);
  float rs = rsqrtf(var + LN_EPS);
  float2 gg = *(const float2*)&g[c2];
  float2 bb = *(const float2*)&beta[c2];
  *(float2*)&out[(size_t)n * 128 + c2] =
      make_float2(dx * rs * gg.x + bb.x, dy * rs * gg.y + bb.y);
}

// ---------------- launch ----------------
extern "C" void kernel_launch(void* const* d_in, const int* in_sizes, int n_in,
                              void* d_out, int out_size, void* d_ws, size_t ws_size,
                              hipStream_t stream) {
  const float* x     = (const float*)d_in[0];
  const int*   ei    = (const int*)  d_in[1];   // int32 or int64 -- detected on device
  const float* W_in  = (const float*)d_in[2];
  const float* b_in  = (const float*)d_in[3];
  const float* Wk1   = (const float*)d_in[6];
  const float* Wv1   = (const float*)d_in[8];
  const float* bv1   = (const float*)d_in[9];
  const float* att1  = (const float*)d_in[10];
  const float* g1    = (const float*)d_in[11];
  const float* beta1 = (const float*)d_in[12];
  const float* Wk2   = (const float*)d_in[15];
  const float* Wv2   = (const float*)d_in[17];
  const float* bv2   = (const float*)d_in[18];
  const float* att2  = (const float*)d_in[19];
  const float* g2    = (const float*)d_in[20];
  const float* beta2 = (const float*)d_in[21];
  const float* W_out = (const float*)d_in[22];
  const float* b_out = (const float*)d_in[23];
  float* zout = (float*)d_out;

  char* base = (char*)d_ws;
  size_t off = 0;
  auto take = [&](size_t bytes) -> void* {
    void* p = base + off;
    off += (bytes + 255) & ~(size_t)255;
    return p;
  };
  float* h1      = (float*)take((size_t)N_NODES * 128 * 4);  // dead after gat0 -> p0
  float* h2      = (float*)take((size_t)N_NODES * 128 * 4);  // LN'd in place (h3)
  float* u       = (float*)take((size_t)N_NODES * 512 * 4);  // vcat1 aliases (dead before)
  float* vcat1   = u;
  float* p1buf   = (float*)take((size_t)N_NODES * 128 * 4);  // K-split partial plane 1
  float* ak2     = (float*)take((size_t)N_NODES * 4 * 4);
  float* Wka1    = (float*)take(128 * NH * 4);
  float* Wka2    = (float*)take(128 * NH * 4);
  float* W2r     = (float*)take(512 * 128 * 4);
  float* mb      = (float*)take(128 * 4);
  int*   counts  = (int*)take((size_t)N_NODES * 4);
  int*   row_ptr = (int*)take((size_t)(N_NODES + 1) * 4);
  int*   fillp   = (int*)take((size_t)N_NODES * 4);
  int*   col_idx = (int*)take((size_t)N_EDGES * 4);
  int*   eflag   = (int*)take(256);
  float* p0buf   = h1;      // h1 dead after gat0 consumes it
  float* h3      = h2;      // ln_res4 is in-place safe

  const int RT = (N_NODES + 63) / 64;   // 313 row tiles

  // CSR build
  hipMemsetAsync(counts, 0, (size_t)N_NODES * 4, stream);
  detect_kernel<<<1, 1024, 0, stream>>>(ei, eflag);
  hist_kernel<<<512, 256, 0, stream>>>(ei, eflag, counts);
  scan_kernel<<<1, 1024, 0, stream>>>(counts, row_ptr, fillp);
  scatter_kernel<<<512, 256, 0, stream>>>(ei, eflag, fillp, col_idx);

  prep_ak_weights<<<2, 256, 0, stream>>>(Wk1, att1, Wk2, att2, Wka1, Wka2);
  prep_w2r<<<64, 256, 0, stream>>>(Wv2, bv2, W2r, mb);

  // h1 = relu(x @ W_in + b_in)
  gemm_sb<1, 128><<<dim3(RT, 2), 256, 0, stream>>>(x, W_in, b_in, h1, 128, 128);
  // vcat1 v-part = h1 @ Wv1 + bv1 ; ak-part = h1 @ Wka1
  gemm_sb<0, 128><<<dim3(RT, 2), 256, 0, stream>>>(h1, Wv1, bv1, vcat1, 128, VC1);
  akgemv<<<(N_NODES + 3) / 4, 256, 0, stream>>>(h1, Wka1, vcat1, 128, VC1);
  // layer 0 aggregation + residual + LN + relu -> h2
  gat0<<<N_NODES / 4, 256, 0, stream>>>(vcat1, row_ptr, col_idx, h1, g1, beta1, h2);
  // layer 1: ak2 then aggregated features u (projection deferred)
  akgemv<<<(N_NODES + 3) / 4, 256, 0, stream>>>(h2, Wka2, ak2, 0, 4);
  gat1_agg<<<N_NODES / 4, 256, 0, stream>>>(h2, ak2, row_ptr, col_idx, u);
  // o2 partials: p0 + p1 = u @ W2r   (2-way K-split, LDS-staged X)
  gemm_ks<<<dim3(RT, 2, 2), 256, 0, stream>>>(u, W2r, p0buf, p1buf);
  // h3 = LN(p0 + p1 + mb + h2) * g2 + beta2   (in place over h2)
  ln_res4<<<N_NODES / 4, 256, 0, stream>>>(p0buf, p1buf, mb, h2, g2, beta2, h3);
  // z = h3 @ W_out + b_out
  gemm_sb<0, 128><<<dim3(RT, 2), 256, 0, stream>>>(h3, W_out, b_out, zout, 128, 128);
}